// Round 10
// baseline (487.900 us; speedup 1.0000x reference)
//
#include <hip/hip_runtime.h>
#include <stdint.h>

#define BATCH 8192
#define DIM   1024            // elements per row; fp8 => also bytes per row
#define NTILE 64              // 8192 / 128 tiles per dimension
#define NPAIR 1056            // sum over bi of ceil((64-bi)/2) pair-blocks
#define CPX2  132             // NPAIR / 8 : pairs per XCD chunk (bijective swizzle)

#define FSZ   ((size_t)BATCH * DIM)   // bytes per feature in Fn (8 MB)
#define PAN   ((size_t)64 * 8192)     // bytes per K-block panel: 64 rowblks x 8 KB
#define OPB   8192                    // bytes per operand tile image (128 rows x 64 kB)

#define FSCALE 8.0f                          // pre-scale before fp8 quant
#define EXPF   (2.0f / (FSCALE * FSCALE))    // exp(2*dot) = exp(acc * EXPF)

typedef int   intx4   __attribute__((ext_vector_type(4)));
typedef float floatx4 __attribute__((ext_vector_type(4)));
typedef long  longx2  __attribute__((ext_vector_type(2)));

__device__ __forceinline__ void async_ld16(const void* g, void* l) {
    __builtin_amdgcn_global_load_lds(
        (__attribute__((address_space(1))) void*)(void*)g,
        (__attribute__((address_space(3))) void*)l,
        16, 0, 0);
}

__device__ __forceinline__ longx2 as_l2(intx4 v) {
    longx2 r;
    __builtin_memcpy(&r, &v, 16);
    return r;
}

// ------------- row L2-normalize: fp32 -> fp8 e4m3 (x FSCALE) -------------
// Round-9 version, unchanged (frag-packed layout for 16x16x32 fp8 MFMA):
//   Fn[f][kb:16][rowblk:64][ g:8 ][ q:4 ][ cl:16 ][16 B]
// chunk (row, kb, q) bytes = elements kb*64+q*8+[0..8) ++ kb*64+32+q*8+[0..8).
__global__ __launch_bounds__(256) void norm_kernel(const float* __restrict__ text,
                                                   const float* __restrict__ image,
                                                   unsigned char* __restrict__ out) {
    const int f = blockIdx.y;
    const float* in = f ? image : text;
    const int row0 = blockIdx.x * 32;         // 32-aligned row group
    const int t    = threadIdx.x;
    const int r32  = t >> 3;                  // row within group, 0..31
    const int sub  = t & 7;                   // 8 threads per row
    const int row  = row0 + r32;
    const float4* src = (const float4*)(in + (size_t)row * DIM);

    const int q   = sub & 3;                  // chunk q owned by this thread
    const int kb0 = sub >> 2;                 // kb parity owned by this thread

    float4 v[8][4];
    float ss = 0.f;
    #pragma unroll
    for (int s = 0; s < 8; ++s) {
        const int fb = (kb0 + 2 * s) * 16 + 2 * q;
        v[s][0] = src[fb];
        v[s][1] = src[fb + 1];
        v[s][2] = src[fb + 8];
        v[s][3] = src[fb + 9];
        #pragma unroll
        for (int u = 0; u < 4; ++u)
            ss += v[s][u].x * v[s][u].x + v[s][u].y * v[s][u].y
                + v[s][u].z * v[s][u].z + v[s][u].w * v[s][u].w;
    }
    ss += __shfl_xor(ss, 1); ss += __shfl_xor(ss, 2); ss += __shfl_xor(ss, 4);
    const float inv = FSCALE / fmaxf(sqrtf(ss), 1e-12f);

    const int rb = row >> 7;
    const int g  = (row & 127) >> 4;
    const int cl = row & 15;
    unsigned char* obase = out + (size_t)f * FSZ + (size_t)rb * OPB
                         + g * 1024 + q * 256 + cl * 16;
    #pragma unroll
    for (int s = 0; s < 8; ++s) {
        intx4 w;
        #pragma unroll
        for (int u = 0; u < 4; ++u) {
            int p = __builtin_amdgcn_cvt_pk_fp8_f32(v[s][u].x * inv, v[s][u].y * inv, 0, false);
            p     = __builtin_amdgcn_cvt_pk_fp8_f32(v[s][u].z * inv, v[s][u].w * inv, p, true);
            w[u] = p;
        }
        *(intx4*)(obase + (size_t)(kb0 + 2 * s) * PAN) = w;   // full 16-B chunk
    }
}

// -------- fused symmetric sim GEMM (fp8 K=32 MFMA), PAIRED TILES --------
// ROUND-10: each block computes TWO adjacent 128^2 tiles (bi,bj0) (bi,bj1=bj0+1)
// sharing one A-panel stage. Rationale (round-9 counters): MfmaUtil 47% with
// MFMA-pipe demand 68us of 126us wall -> idle time is per-barrier-interval
// exposure (only 32 MFMAs/wave between barriers). Pairing doubles MFMA per
// interval (64/wave) and cuts staged bytes per output 16->12 B, while keeping
// 3 blocks/CU (LDS 48 KB dbuf) and 256 threads (512-thread VGPR cliff, r3/4).
// Wave grid 2x2: wm = 64-row half, wn = WHICH B subtile (wn waves only touch
// their own B tile). acc[4][8] = 128 VGPR; B-frags streamed in 4-frag halves;
// __launch_bounds__(256,3) caps VGPR at 170. Spill tripwire: WRITE_SIZE >> 8MB.
// Epilogue: NO global atomics; slots bj0/bj1 row-parts, slot bi col-parts x2
// -> exact disjoint cover of P[f][u][slot][g] (diag: skip subtile-0 col part;
// odd-tail single blocks: bj1 clamped, subtile-1 stores skipped).
__global__ __launch_bounds__(256, 3) void sim_kernel(const unsigned char* __restrict__ F,
                                                     const int* __restrict__ label,
                                                     float* __restrict__ P) {
    // bijective XCD chunk swizzle: 1056 = 8 * 132
    int l = (blockIdx.x & 7) * CPX2 + (blockIdx.x >> 3);
    int bi = 0;
    for (;;) {
        const int npb = (NTILE - bi + 1) >> 1;   // pairs in row bi
        if (l < npb) break;
        l -= npb; ++bi;
    }
    const int  bj0  = bi + 2 * l;
    int        bj1  = bj0 + 1;
    const bool has1 = (bj1 < NTILE);
    if (!has1) bj1 = bj0;                        // tail: stage same data, skip stores
    const bool diag = (bj0 == bi);

    const int f = blockIdx.z;
    const int rowTile = bi * 128;

    // double-buffered LDS: A 8 KB, B0+B1 16 KB per buffer -> 48 KB total
    __shared__ __align__(16) unsigned char As[2][8192];
    __shared__ __align__(16) unsigned char Bs[2][16384];

    const int tid  = threadIdx.x;
    const int lane = tid & 63;
    const int wave = tid >> 6;
    const int wm   = wave >> 1;        // 64-row half
    const int wn   = wave & 1;         // B subtile (0 -> bj0, 1 -> bj1)
    const int quad = lane >> 4;
    const int cl   = lane & 15;

    // staging: per kb each wave copies 2 KB of each of A, B0, B1 (6 x 1-KB
    // contiguous global_load_lds; pure linear copy in the frag-packed layout).
    const unsigned char* gA  = F + (size_t)f * FSZ + (size_t)bi  * OPB + wave * 2048 + lane * 16;
    const unsigned char* gB0 = F + (size_t)f * FSZ + (size_t)bj0 * OPB + wave * 2048 + lane * 16;
    const unsigned char* gB1 = F + (size_t)f * FSZ + (size_t)bj1 * OPB + wave * 2048 + lane * 16;
    unsigned char* lA  = As[0] + wave * 2048 + lane * 16;
    unsigned char* lB0 = Bs[0] + wave * 2048 + lane * 16;
    unsigned char* lB1 = Bs[0] + 8192 + wave * 2048 + lane * 16;

    floatx4 acc[4][8];
    const floatx4 z4 = {0.f, 0.f, 0.f, 0.f};
    #pragma unroll
    for (int mi = 0; mi < 4; ++mi)
        #pragma unroll
        for (int nj = 0; nj < 8; ++nj) acc[mi][nj] = z4;

    // frag read bases (linear, conflict-free: wave reads 1 KB contiguous)
    const unsigned char* aF = As[0] + quad * 256 + cl * 16;
    const unsigned char* bF = Bs[0] + wn * 8192 + quad * 256 + cl * 16;

    // ---- prologue: stage kb 0 (6 loads/wave in flight) ----
    async_ld16(gA, lA);                 async_ld16(gA + 1024, lA + 1024);
    async_ld16(gB0, lB0);               async_ld16(gB0 + 1024, lB0 + 1024);
    async_ld16(gB1, lB1);               async_ld16(gB1 + 1024, lB1 + 1024);
    gA += PAN; gB0 += PAN; gB1 += PAN;

    #pragma unroll
    for (int kb = 0; kb < 16; ++kb) {
        const int cur = kb & 1;
        const int nxt = cur ^ 1;
        if (kb < 15) {
            async_ld16(gA,  lA  + nxt * 8192);  async_ld16(gA + 1024,  lA  + nxt * 8192 + 1024);
            async_ld16(gB0, lB0 + nxt * 16384); async_ld16(gB0 + 1024, lB0 + nxt * 16384 + 1024);
            async_ld16(gB1, lB1 + nxt * 16384); async_ld16(gB1 + 1024, lB1 + nxt * 16384 + 1024);
            gA += PAN; gB0 += PAN; gB1 += PAN;
            asm volatile("s_waitcnt vmcnt(6)" ::: "memory");   // this wave's kb loads
        } else {
            asm volatile("s_waitcnt vmcnt(0)" ::: "memory");
        }
        __builtin_amdgcn_s_barrier();        // all waves' kb data in LDS
        __builtin_amdgcn_sched_barrier(0);   // keep ds_reads below the barrier

        const unsigned char* aB = aF + cur * 8192 + (wm * 4) * 1024;
        const unsigned char* bB = bF + cur * 16384;

        __builtin_amdgcn_s_setprio(1);
        #pragma unroll
        for (int h = 0; h < 2; ++h) {        // B streamed in 4-frag halves (reg cap)
            longx2 bfr[4];
            #pragma unroll
            for (int j = 0; j < 4; ++j)
                bfr[j] = as_l2(*(const intx4*)(bB + (h * 4 + j) * 1024));
            #pragma unroll
            for (int mi = 0; mi < 4; ++mi) {
                longx2 afr = as_l2(*(const intx4*)(aB + mi * 1024));
                #pragma unroll
                for (int j = 0; j < 4; ++j) {
                    acc[mi][h * 4 + j] = __builtin_amdgcn_mfma_f32_16x16x32_fp8_fp8(
                        afr[0], bfr[j][0], acc[mi][h * 4 + j], 0, 0, 0);
                    acc[mi][h * 4 + j] = __builtin_amdgcn_mfma_f32_16x16x32_fp8_fp8(
                        afr[1], bfr[j][1], acc[mi][h * 4 + j], 0, 0, 0);
                }
            }
        }
        __builtin_amdgcn_s_setprio(0);
        __builtin_amdgcn_sched_barrier(0);   // keep reads/MFMA above the barrier
        __builtin_amdgcn_s_barrier();        // buf[cur] free for next prefetch
    }

    // ---- epilogue: e = exp(acc*EXPF), eye mask (diag, subtile 0 only),
    //      block-local LDS reduction, conflict-free partial stores ----
    __syncthreads();                      // all frag reads done; As reusable
    float* red = (float*)As;              // 6 KB needed, 16 KB available
    // layout (floats): [0..256)     rowR: wn*128 + rowLoc
    //                  [256..512)   rowN
    //                  [512..1024)  colR: wn*256 + wm*128 + colLoc
    //                  [1024..1536) colN
    // every entry written by exactly one lane -> plain ds_write, no init.

    const int colTileW = (wn ? bj1 : bj0) * 128;
    int   colgv[8];
    float wRcv[8];
    #pragma unroll
    for (int nj = 0; nj < 8; ++nj) {
        colgv[nj] = colTileW + nj * 16 + cl;
        wRcv[nj]  = (label[colgv[nj]] != 0) ? 1.0f : 0.0f;
    }

    float colRa[8] = {0.f, 0.f, 0.f, 0.f, 0.f, 0.f, 0.f, 0.f};
    float colNa[8] = {0.f, 0.f, 0.f, 0.f, 0.f, 0.f, 0.f, 0.f};
    const bool eyeW = diag && (wn == 0);

    #pragma unroll
    for (int mi = 0; mi < 4; ++mi) {
        #pragma unroll
        for (int r = 0; r < 4; ++r) {
            const int rowLoc = wm * 64 + mi * 16 + quad * 4 + r;   // C/D: row=quad*4+reg
            const int rowg   = rowTile + rowLoc;
            const float wRr  = (label[rowg] != 0) ? 1.0f : 0.0f;
            float pR = 0.f, pN = 0.f;
            #pragma unroll
            for (int nj = 0; nj < 8; ++nj) {
                float c = acc[mi][nj][r];
                float e = __expf(c * EXPF);
                if (eyeW) e = (rowg == colgv[nj]) ? 0.0f : e;      // eye mask
                pR += wRcv[nj] * e;
                pN += (1.0f - wRcv[nj]) * e;
                colRa[nj] += wRr * e;
                colNa[nj] += (1.0f - wRr) * e;
            }
            #pragma unroll
            for (int m = 1; m < 16; m <<= 1) {        // reduce the 16 cl lanes
                pR += __shfl_xor(pR, m);
                pN += __shfl_xor(pN, m);
            }
            if (cl == 0) {
                red[wn * 128 + rowLoc]       = pR;
                red[256 + wn * 128 + rowLoc] = pN;
            }
        }
    }

    #pragma unroll
    for (int nj = 0; nj < 8; ++nj) {
        float cR = colRa[nj], cN = colNa[nj];
        cR += __shfl_xor(cR, 16); cN += __shfl_xor(cN, 16);       // reduce quads
        cR += __shfl_xor(cR, 32); cN += __shfl_xor(cN, 32);
        if (quad == 0) {
            red[512  + wn * 256 + wm * 128 + nj * 16 + cl] = cR;
            red[1024 + wn * 256 + wm * 128 + nj * 16 + cl] = cN;
        }
    }

    __syncthreads();
    // P layout: [f][u(R=0,N=1)][slot 0..63][g 0..8191]
    float* Pr = P + ((size_t)f * 2 + 0) * (size_t)NTILE * BATCH;
    float* Pn = P + ((size_t)f * 2 + 1) * (size_t)NTILE * BATCH;
    if (tid < 128) {
        Pr[(size_t)bj0 * BATCH + rowTile + tid] = red[tid];
        Pn[(size_t)bj0 * BATCH + rowTile + tid] = red[256 + tid];
        if (has1) {
            Pr[(size_t)bj1 * BATCH + rowTile + tid] = red[128 + tid];
            Pn[(size_t)bj1 * BATCH + rowTile + tid] = red[384 + tid];
        }
        if (!diag) {
            Pr[(size_t)bi * BATCH + bj0 * 128 + tid] = red[512 + tid] + red[640 + tid];
            Pn[(size_t)bi * BATCH + bj0 * 128 + tid] = red[1024 + tid] + red[1152 + tid];
        }
        if (has1) {
            Pr[(size_t)bi * BATCH + bj1 * 128 + tid] = red[768 + tid] + red[896 + tid];
            Pn[(size_t)bi * BATCH + bj1 * 128 + tid] = red[1280 + tid] + red[1408 + tid];
        }
    }
}

// -------- final: 64-slot partial reduce + per-row loss + global reduce --------
__global__ __launch_bounds__(256) void loss_kernel(const float* __restrict__ P,
                                                   const int* __restrict__ label,
                                                   float* __restrict__ out) {
    const int idx = blockIdx.x * 256 + threadIdx.x;   // 0..16383 = (f, i)
    const int f = idx >> 13;
    const int i = idx & (BATCH - 1);
    const int lab = label[i];
    const float* Pr = P + ((size_t)f * 2 + 0) * (size_t)NTILE * BATCH;
    const float* Pn = Pr + (size_t)NTILE * BATCH;
    float sR = 0.f, sN = 0.f;
    #pragma unroll 8
    for (int s = 0; s < NTILE; ++s) {
        sR += Pr[(size_t)s * BATCH + i];
        sN += Pn[(size_t)s * BATCH + i];
    }
    const float own = lab ? sR : sN;
    const float oth = lab ? sN : sR;
    float t = -logf(own / (own + oth) + 1e-8f) * (1.0f / 4096.0f);
    #pragma unroll
    for (int m = 32; m >= 1; m >>= 1) t += __shfl_xor(t, m);
    __shared__ float red[4];
    if ((threadIdx.x & 63) == 0) red[threadIdx.x >> 6] = t;
    __syncthreads();
    if (threadIdx.x == 0) atomicAdd(out, red[0] + red[1] + red[2] + red[3]);
}

extern "C" void kernel_launch(void* const* d_in, const int* in_sizes, int n_in,
                              void* d_out, int out_size, void* d_ws, size_t ws_size,
                              hipStream_t stream) {
    const float* text  = (const float*)d_in[0];
    const float* image = (const float*)d_in[1];
    const int*   label = (const int*)d_in[2];
    float* out = (float*)d_out;

    // workspace: Fn[2][16][64rb][8KB] fp8 (16 MB), then P[2][2][64][8192] f32 (16 MB)
    unsigned char* Fn = (unsigned char*)d_ws;
    float* P = (float*)((char*)d_ws + (size_t)2 * BATCH * DIM);

    hipMemsetAsync(out, 0, sizeof(float), stream);

    dim3 ngrid(BATCH / 32, 2);
    norm_kernel<<<ngrid, 256, 0, stream>>>(text, image, Fn);

    dim3 grid(NPAIR, 1, 2);
    sim_kernel<<<grid, 256, 0, stream>>>(Fn, label, P);

    loss_kernel<<<(2 * BATCH) / 256, 256, 0, stream>>>(P, label, out);
}

// Round 11
// 310.344 us; speedup vs baseline: 1.5721x; 1.5721x over previous
//
#include <hip/hip_runtime.h>
#include <stdint.h>

#define BATCH 8192
#define DIM   1024            // elements per row; fp8 => also bytes per row
#define NTILE 64              // 8192 / 128 tiles per dimension
#define NPAIR 1056            // sum over bi of ceil((64-bi)/2) pair-blocks
#define CPX2  132             // NPAIR / 8 : pairs per XCD chunk (bijective swizzle)

#define FSZ   ((size_t)BATCH * DIM)   // bytes per feature in Fn (8 MB)
#define PAN   ((size_t)64 * 8192)     // bytes per K-block panel: 64 rowblks x 8 KB
#define OPB   8192                    // bytes per operand tile image (128 rows x 64 kB)

#define FSCALE 8.0f                          // pre-scale before fp8 quant
#define EXPF   (2.0f / (FSCALE * FSCALE))    // exp(2*dot) = exp(acc * EXPF)

typedef int   intx4   __attribute__((ext_vector_type(4)));
typedef float floatx4 __attribute__((ext_vector_type(4)));
typedef long  longx2  __attribute__((ext_vector_type(2)));

__device__ __forceinline__ void async_ld16(const void* g, void* l) {
    __builtin_amdgcn_global_load_lds(
        (__attribute__((address_space(1))) void*)(void*)g,
        (__attribute__((address_space(3))) void*)l,
        16, 0, 0);
}

__device__ __forceinline__ longx2 as_l2(intx4 v) {
    longx2 r;
    __builtin_memcpy(&r, &v, 16);
    return r;
}

// ------------- row L2-normalize: fp32 -> fp8 e4m3 (x FSCALE) -------------
// Round-9 version, unchanged (frag-packed layout for 16x16x32 fp8 MFMA):
//   Fn[f][kb:16][rowblk:64][ g:8 ][ q:4 ][ cl:16 ][16 B]
// chunk (row, kb, q) bytes = elements kb*64+q*8+[0..8) ++ kb*64+32+q*8+[0..8).
__global__ __launch_bounds__(256) void norm_kernel(const float* __restrict__ text,
                                                   const float* __restrict__ image,
                                                   unsigned char* __restrict__ out) {
    const int f = blockIdx.y;
    const float* in = f ? image : text;
    const int row0 = blockIdx.x * 32;         // 32-aligned row group
    const int t    = threadIdx.x;
    const int r32  = t >> 3;                  // row within group, 0..31
    const int sub  = t & 7;                   // 8 threads per row
    const int row  = row0 + r32;
    const float4* src = (const float4*)(in + (size_t)row * DIM);

    const int q   = sub & 3;                  // chunk q owned by this thread
    const int kb0 = sub >> 2;                 // kb parity owned by this thread

    float4 v[8][4];
    float ss = 0.f;
    #pragma unroll
    for (int s = 0; s < 8; ++s) {
        const int fb = (kb0 + 2 * s) * 16 + 2 * q;
        v[s][0] = src[fb];
        v[s][1] = src[fb + 1];
        v[s][2] = src[fb + 8];
        v[s][3] = src[fb + 9];
        #pragma unroll
        for (int u = 0; u < 4; ++u)
            ss += v[s][u].x * v[s][u].x + v[s][u].y * v[s][u].y
                + v[s][u].z * v[s][u].z + v[s][u].w * v[s][u].w;
    }
    ss += __shfl_xor(ss, 1); ss += __shfl_xor(ss, 2); ss += __shfl_xor(ss, 4);
    const float inv = FSCALE / fmaxf(sqrtf(ss), 1e-12f);

    const int rb = row >> 7;
    const int g  = (row & 127) >> 4;
    const int cl = row & 15;
    unsigned char* obase = out + (size_t)f * FSZ + (size_t)rb * OPB
                         + g * 1024 + q * 256 + cl * 16;
    #pragma unroll
    for (int s = 0; s < 8; ++s) {
        intx4 w;
        #pragma unroll
        for (int u = 0; u < 4; ++u) {
            int p = __builtin_amdgcn_cvt_pk_fp8_f32(v[s][u].x * inv, v[s][u].y * inv, 0, false);
            p     = __builtin_amdgcn_cvt_pk_fp8_f32(v[s][u].z * inv, v[s][u].w * inv, p, true);
            w[u] = p;
        }
        *(intx4*)(obase + (size_t)(kb0 + 2 * s) * PAN) = w;   // full 16-B chunk
    }
}

// -------- fused symmetric sim GEMM (fp8 K=32 MFMA), PAIRED TILES --------
// ROUND-11: round-10 structure with the register cap removed. Empirical rule
// from r7/r10: __launch_bounds__(256,3) clamps the allocator at ~84 VGPR
// (twice as tight as the 512/3~170 model) -> acc[4][8]=128 spilled (WRITE 1.08
// GB, FETCH 555 MB). Plain __launch_bounds__(256) lets the allocator take the
// ~165 the main loop needs (r2 precedent: 248); 512/165 -> 3 waves/SIMD, which
// matches the 48-KB-LDS limit of 3 blocks/CU, so round-6 concurrency is kept.
// Each block computes TWO adjacent 128^2 tiles sharing one A-panel stage:
// 64 MFMAs/wave per barrier interval (2x round 9) and 12 B staged per output.
// Epilogue: NO global atomics; slots bj0/bj1 row-parts, slot bi col-parts x2
// -> exact disjoint cover of P[f][u][slot][g] (diag: skip subtile-0 col part;
// odd-tail single blocks: bj1 clamped, subtile-1 stores skipped).
__global__ __launch_bounds__(256) void sim_kernel(const unsigned char* __restrict__ F,
                                                  const int* __restrict__ label,
                                                  float* __restrict__ P) {
    // bijective XCD chunk swizzle: 1056 = 8 * 132
    int l = (blockIdx.x & 7) * CPX2 + (blockIdx.x >> 3);
    int bi = 0;
    for (;;) {
        const int npb = (NTILE - bi + 1) >> 1;   // pairs in row bi
        if (l < npb) break;
        l -= npb; ++bi;
    }
    const int  bj0  = bi + 2 * l;
    int        bj1  = bj0 + 1;
    const bool has1 = (bj1 < NTILE);
    if (!has1) bj1 = bj0;                        // tail: stage same data, skip stores
    const bool diag = (bj0 == bi);

    const int f = blockIdx.z;
    const int rowTile = bi * 128;

    // double-buffered LDS: A 8 KB, B0+B1 16 KB per buffer -> 48 KB total
    __shared__ __align__(16) unsigned char As[2][8192];
    __shared__ __align__(16) unsigned char Bs[2][16384];

    const int tid  = threadIdx.x;
    const int lane = tid & 63;
    const int wave = tid >> 6;
    const int wm   = wave >> 1;        // 64-row half
    const int wn   = wave & 1;         // B subtile (0 -> bj0, 1 -> bj1)
    const int quad = lane >> 4;
    const int cl   = lane & 15;

    // staging: per kb each wave copies 2 KB of each of A, B0, B1 (6 x 1-KB
    // contiguous global_load_lds; pure linear copy in the frag-packed layout).
    const unsigned char* gA  = F + (size_t)f * FSZ + (size_t)bi  * OPB + wave * 2048 + lane * 16;
    const unsigned char* gB0 = F + (size_t)f * FSZ + (size_t)bj0 * OPB + wave * 2048 + lane * 16;
    const unsigned char* gB1 = F + (size_t)f * FSZ + (size_t)bj1 * OPB + wave * 2048 + lane * 16;
    unsigned char* lA  = As[0] + wave * 2048 + lane * 16;
    unsigned char* lB0 = Bs[0] + wave * 2048 + lane * 16;
    unsigned char* lB1 = Bs[0] + 8192 + wave * 2048 + lane * 16;

    floatx4 acc[4][8];
    const floatx4 z4 = {0.f, 0.f, 0.f, 0.f};
    #pragma unroll
    for (int mi = 0; mi < 4; ++mi)
        #pragma unroll
        for (int nj = 0; nj < 8; ++nj) acc[mi][nj] = z4;

    // frag read bases (linear, conflict-free: wave reads 1 KB contiguous)
    const unsigned char* aF = As[0] + quad * 256 + cl * 16;
    const unsigned char* bF = Bs[0] + wn * 8192 + quad * 256 + cl * 16;

    // ---- prologue: stage kb 0 (6 loads/wave in flight) ----
    async_ld16(gA, lA);                 async_ld16(gA + 1024, lA + 1024);
    async_ld16(gB0, lB0);               async_ld16(gB0 + 1024, lB0 + 1024);
    async_ld16(gB1, lB1);               async_ld16(gB1 + 1024, lB1 + 1024);
    gA += PAN; gB0 += PAN; gB1 += PAN;

    #pragma unroll
    for (int kb = 0; kb < 16; ++kb) {
        const int cur = kb & 1;
        const int nxt = cur ^ 1;
        if (kb < 15) {
            async_ld16(gA,  lA  + nxt * 8192);  async_ld16(gA + 1024,  lA  + nxt * 8192 + 1024);
            async_ld16(gB0, lB0 + nxt * 16384); async_ld16(gB0 + 1024, lB0 + nxt * 16384 + 1024);
            async_ld16(gB1, lB1 + nxt * 16384); async_ld16(gB1 + 1024, lB1 + nxt * 16384 + 1024);
            gA += PAN; gB0 += PAN; gB1 += PAN;
            asm volatile("s_waitcnt vmcnt(6)" ::: "memory");   // this wave's kb loads
        } else {
            asm volatile("s_waitcnt vmcnt(0)" ::: "memory");
        }
        __builtin_amdgcn_s_barrier();        // all waves' kb data in LDS
        __builtin_amdgcn_sched_barrier(0);   // keep ds_reads below the barrier

        const unsigned char* aB = aF + cur * 8192 + (wm * 4) * 1024;
        const unsigned char* bB = bF + cur * 16384;

        __builtin_amdgcn_s_setprio(1);
        #pragma unroll
        for (int h = 0; h < 2; ++h) {        // B streamed in 4-frag halves (reg cap)
            longx2 bfr[4];
            #pragma unroll
            for (int j = 0; j < 4; ++j)
                bfr[j] = as_l2(*(const intx4*)(bB + (h * 4 + j) * 1024));
            #pragma unroll
            for (int mi = 0; mi < 4; ++mi) {
                longx2 afr = as_l2(*(const intx4*)(aB + mi * 1024));
                #pragma unroll
                for (int j = 0; j < 4; ++j) {
                    acc[mi][h * 4 + j] = __builtin_amdgcn_mfma_f32_16x16x32_fp8_fp8(
                        afr[0], bfr[j][0], acc[mi][h * 4 + j], 0, 0, 0);
                    acc[mi][h * 4 + j] = __builtin_amdgcn_mfma_f32_16x16x32_fp8_fp8(
                        afr[1], bfr[j][1], acc[mi][h * 4 + j], 0, 0, 0);
                }
            }
        }
        __builtin_amdgcn_s_setprio(0);
        __builtin_amdgcn_sched_barrier(0);   // keep reads/MFMA above the barrier
        __builtin_amdgcn_s_barrier();        // buf[cur] free for next prefetch
    }

    // ---- epilogue: e = exp(acc*EXPF), eye mask (diag, subtile 0 only),
    //      block-local LDS reduction, conflict-free partial stores ----
    __syncthreads();                      // all frag reads done; As reusable
    float* red = (float*)As;              // 6 KB needed, 16 KB available
    // layout (floats): [0..256)     rowR: wn*128 + rowLoc
    //                  [256..512)   rowN
    //                  [512..1024)  colR: wn*256 + wm*128 + colLoc
    //                  [1024..1536) colN
    // every entry written by exactly one lane -> plain ds_write, no init.

    const int colTileW = (wn ? bj1 : bj0) * 128;
    int   colgv[8];
    float wRcv[8];
    #pragma unroll
    for (int nj = 0; nj < 8; ++nj) {
        colgv[nj] = colTileW + nj * 16 + cl;
        wRcv[nj]  = (label[colgv[nj]] != 0) ? 1.0f : 0.0f;
    }

    float colRa[8] = {0.f, 0.f, 0.f, 0.f, 0.f, 0.f, 0.f, 0.f};
    float colNa[8] = {0.f, 0.f, 0.f, 0.f, 0.f, 0.f, 0.f, 0.f};
    const bool eyeW = diag && (wn == 0);

    #pragma unroll
    for (int mi = 0; mi < 4; ++mi) {
        #pragma unroll
        for (int r = 0; r < 4; ++r) {
            const int rowLoc = wm * 64 + mi * 16 + quad * 4 + r;   // C/D: row=quad*4+reg
            const int rowg   = rowTile + rowLoc;
            const float wRr  = (label[rowg] != 0) ? 1.0f : 0.0f;
            float pR = 0.f, pN = 0.f;
            #pragma unroll
            for (int nj = 0; nj < 8; ++nj) {
                float c = acc[mi][nj][r];
                float e = __expf(c * EXPF);
                if (eyeW) e = (rowg == colgv[nj]) ? 0.0f : e;      // eye mask
                pR += wRcv[nj] * e;
                pN += (1.0f - wRcv[nj]) * e;
                colRa[nj] += wRr * e;
                colNa[nj] += (1.0f - wRr) * e;
            }
            #pragma unroll
            for (int m = 1; m < 16; m <<= 1) {        // reduce the 16 cl lanes
                pR += __shfl_xor(pR, m);
                pN += __shfl_xor(pN, m);
            }
            if (cl == 0) {
                red[wn * 128 + rowLoc]       = pR;
                red[256 + wn * 128 + rowLoc] = pN;
            }
        }
    }

    #pragma unroll
    for (int nj = 0; nj < 8; ++nj) {
        float cR = colRa[nj], cN = colNa[nj];
        cR += __shfl_xor(cR, 16); cN += __shfl_xor(cN, 16);       // reduce quads
        cR += __shfl_xor(cR, 32); cN += __shfl_xor(cN, 32);
        if (quad == 0) {
            red[512  + wn * 256 + wm * 128 + nj * 16 + cl] = cR;
            red[1024 + wn * 256 + wm * 128 + nj * 16 + cl] = cN;
        }
    }

    __syncthreads();
    // P layout: [f][u(R=0,N=1)][slot 0..63][g 0..8191]
    float* Pr = P + ((size_t)f * 2 + 0) * (size_t)NTILE * BATCH;
    float* Pn = P + ((size_t)f * 2 + 1) * (size_t)NTILE * BATCH;
    if (tid < 128) {
        Pr[(size_t)bj0 * BATCH + rowTile + tid] = red[tid];
        Pn[(size_t)bj0 * BATCH + rowTile + tid] = red[256 + tid];
        if (has1) {
            Pr[(size_t)bj1 * BATCH + rowTile + tid] = red[128 + tid];
            Pn[(size_t)bj1 * BATCH + rowTile + tid] = red[384 + tid];
        }
        if (!diag) {
            Pr[(size_t)bi * BATCH + bj0 * 128 + tid] = red[512 + tid] + red[640 + tid];
            Pn[(size_t)bi * BATCH + bj0 * 128 + tid] = red[1024 + tid] + red[1152 + tid];
        }
        if (has1) {
            Pr[(size_t)bi * BATCH + bj1 * 128 + tid] = red[768 + tid] + red[896 + tid];
            Pn[(size_t)bi * BATCH + bj1 * 128 + tid] = red[1280 + tid] + red[1408 + tid];
        }
    }
}

// -------- final: 64-slot partial reduce + per-row loss + global reduce --------
__global__ __launch_bounds__(256) void loss_kernel(const float* __restrict__ P,
                                                   const int* __restrict__ label,
                                                   float* __restrict__ out) {
    const int idx = blockIdx.x * 256 + threadIdx.x;   // 0..16383 = (f, i)
    const int f = idx >> 13;
    const int i = idx & (BATCH - 1);
    const int lab = label[i];
    const float* Pr = P + ((size_t)f * 2 + 0) * (size_t)NTILE * BATCH;
    const float* Pn = Pr + (size_t)NTILE * BATCH;
    float sR = 0.f, sN = 0.f;
    #pragma unroll 8
    for (int s = 0; s < NTILE; ++s) {
        sR += Pr[(size_t)s * BATCH + i];
        sN += Pn[(size_t)s * BATCH + i];
    }
    const float own = lab ? sR : sN;
    const float oth = lab ? sN : sR;
    float t = -logf(own / (own + oth) + 1e-8f) * (1.0f / 4096.0f);
    #pragma unroll
    for (int m = 32; m >= 1; m >>= 1) t += __shfl_xor(t, m);
    __shared__ float red[4];
    if ((threadIdx.x & 63) == 0) red[threadIdx.x >> 6] = t;
    __syncthreads();
    if (threadIdx.x == 0) atomicAdd(out, red[0] + red[1] + red[2] + red[3]);
}

extern "C" void kernel_launch(void* const* d_in, const int* in_sizes, int n_in,
                              void* d_out, int out_size, void* d_ws, size_t ws_size,
                              hipStream_t stream) {
    const float* text  = (const float*)d_in[0];
    const float* image = (const float*)d_in[1];
    const int*   label = (const int*)d_in[2];
    float* out = (float*)d_out;

    // workspace: Fn[2][16][64rb][8KB] fp8 (16 MB), then P[2][2][64][8192] f32 (16 MB)
    unsigned char* Fn = (unsigned char*)d_ws;
    float* P = (float*)((char*)d_ws + (size_t)2 * BATCH * DIM);

    hipMemsetAsync(out, 0, sizeof(float), stream);

    dim3 ngrid(BATCH / 32, 2);
    norm_kernel<<<ngrid, 256, 0, stream>>>(text, image, Fn);

    dim3 grid(NPAIR, 1, 2);
    sim_kernel<<<grid, 256, 0, stream>>>(Fn, label, P);

    loss_kernel<<<(2 * BATCH) / 256, 256, 0, stream>>>(P, label, out);
}

// Round 12
// 223.538 us; speedup vs baseline: 2.1826x; 1.3883x over previous
//
#include <hip/hip_runtime.h>
#include <stdint.h>

#define BATCH 8192
#define DIM   1024            // elements per row; fp8 => also bytes per row
#define NTILE 64              // 8192 / 128 tiles per dimension
#define NPAIR 1056            // sum over bi of ceil((64-bi)/2) pair-blocks
#define CPX2  132             // NPAIR / 8 : pairs per XCD chunk (bijective swizzle)

#define FSZ   ((size_t)BATCH * DIM)   // bytes per feature in Fn (8 MB)
#define PAN   ((size_t)64 * 8192)     // bytes per K-block panel: 64 rowblks x 8 KB
#define OPB   8192                    // bytes per operand tile image (128 rows x 64 kB)

#define FSCALE 8.0f                          // pre-scale before fp8 quant
#define EXPF   (2.0f / (FSCALE * FSCALE))    // exp(2*dot) = exp(acc * EXPF)

typedef int   intx4   __attribute__((ext_vector_type(4)));
typedef float floatx4 __attribute__((ext_vector_type(4)));
typedef long  longx2  __attribute__((ext_vector_type(2)));

__device__ __forceinline__ void async_ld16(const void* g, void* l) {
    __builtin_amdgcn_global_load_lds(
        (__attribute__((address_space(1))) void*)(void*)g,
        (__attribute__((address_space(3))) void*)l,
        16, 0, 0);
}

__device__ __forceinline__ longx2 as_l2(intx4 v) {
    longx2 r;
    __builtin_memcpy(&r, &v, 16);
    return r;
}

// ------------- row L2-normalize: fp32 -> fp8 e4m3 (x FSCALE) -------------
// Round-9 version, unchanged (frag-packed layout for 16x16x32 fp8 MFMA):
//   Fn[f][kb:16][rowblk:64][ g:8 ][ q:4 ][ cl:16 ][16 B]
// chunk (row, kb, q) bytes = elements kb*64+q*8+[0..8) ++ kb*64+32+q*8+[0..8).
__global__ __launch_bounds__(256) void norm_kernel(const float* __restrict__ text,
                                                   const float* __restrict__ image,
                                                   unsigned char* __restrict__ out) {
    const int f = blockIdx.y;
    const float* in = f ? image : text;
    const int row0 = blockIdx.x * 32;         // 32-aligned row group
    const int t    = threadIdx.x;
    const int r32  = t >> 3;                  // row within group, 0..31
    const int sub  = t & 7;                   // 8 threads per row
    const int row  = row0 + r32;
    const float4* src = (const float4*)(in + (size_t)row * DIM);

    const int q   = sub & 3;                  // chunk q owned by this thread
    const int kb0 = sub >> 2;                 // kb parity owned by this thread

    float4 v[8][4];
    float ss = 0.f;
    #pragma unroll
    for (int s = 0; s < 8; ++s) {
        const int fb = (kb0 + 2 * s) * 16 + 2 * q;
        v[s][0] = src[fb];
        v[s][1] = src[fb + 1];
        v[s][2] = src[fb + 8];
        v[s][3] = src[fb + 9];
        #pragma unroll
        for (int u = 0; u < 4; ++u)
            ss += v[s][u].x * v[s][u].x + v[s][u].y * v[s][u].y
                + v[s][u].z * v[s][u].z + v[s][u].w * v[s][u].w;
    }
    ss += __shfl_xor(ss, 1); ss += __shfl_xor(ss, 2); ss += __shfl_xor(ss, 4);
    const float inv = FSCALE / fmaxf(sqrtf(ss), 1e-12f);

    const int rb = row >> 7;
    const int g  = (row & 127) >> 4;
    const int cl = row & 15;
    unsigned char* obase = out + (size_t)f * FSZ + (size_t)rb * OPB
                         + g * 1024 + q * 256 + cl * 16;
    #pragma unroll
    for (int s = 0; s < 8; ++s) {
        intx4 w;
        #pragma unroll
        for (int u = 0; u < 4; ++u) {
            int p = __builtin_amdgcn_cvt_pk_fp8_f32(v[s][u].x * inv, v[s][u].y * inv, 0, false);
            p     = __builtin_amdgcn_cvt_pk_fp8_f32(v[s][u].z * inv, v[s][u].w * inv, p, true);
            w[u] = p;
        }
        *(intx4*)(obase + (size_t)(kb0 + 2 * s) * PAN) = w;   // full 16-B chunk
    }
}

// -------- fused symmetric sim GEMM (fp8 K=32 MFMA), PAIRED TILES, 8 WAVES ----
// ROUND-12: pairing WITHOUT raising per-wave registers. r11 lesson: acc[4][8]
// (176 VGPR) dropped residency 12 -> 8 waves/CU and LOST (126 -> 215 us);
// concurrency > density on this kernel. Here: 512 threads / 8 waves on a
// 128x256 tile, each wave owns 64x64 -> acc[4][4] = 64 VGPR (bit-identical
// inner loop to round 6, the proven 64-reg shape; r3/r4's 512-thread 128-VGPR
// cap is harmless at ~80 needed). Residency: 48-KB LDS -> 3 blocks/CU = 24
// waves/CU (2x round 9); staged bytes per MFMA drop 128 -> 96 B (shared
// A-panel). Staging: 3 x 1-KB contiguous global_load_lds per wave per kb,
// counted vmcnt(3). Epilogue: NO global atomics; slots bj0/bj1 row-parts,
// slot bi col-parts -> exact disjoint cover (diag skips subtile-0 col part;
// odd-tail blocks clamp bj1 and skip subtile-1 stores).
__global__ __launch_bounds__(512) void sim_kernel(const unsigned char* __restrict__ F,
                                                  const int* __restrict__ label,
                                                  float* __restrict__ P) {
    // bijective XCD chunk swizzle: 1056 = 8 * 132
    int l = (blockIdx.x & 7) * CPX2 + (blockIdx.x >> 3);
    int bi = 0;
    for (;;) {
        const int npb = (NTILE - bi + 1) >> 1;   // pairs in row bi
        if (l < npb) break;
        l -= npb; ++bi;
    }
    const int  bj0  = bi + 2 * l;
    int        bj1  = bj0 + 1;
    const bool has1 = (bj1 < NTILE);
    if (!has1) bj1 = bj0;                        // tail: stage same data, skip stores
    const bool diag = (bj0 == bi);

    const int f = blockIdx.z;
    const int rowTile = bi * 128;

    // double-buffered LDS: A 8 KB, B0+B1 16 KB per buffer -> 48 KB total
    __shared__ __align__(16) unsigned char As[2][8192];
    __shared__ __align__(16) unsigned char Bs[2][16384];

    const int tid  = threadIdx.x;
    const int lane = tid & 63;
    const int wave = tid >> 6;         // 0..7
    const int wm   = wave >> 2;        // 64-row half of the 128 rows
    const int wn   = wave & 3;         // 64-col quarter of the 256 cols
    const int sb   = wn >> 1;          // B subtile (0 -> bj0, 1 -> bj1)
    const int hf   = wn & 1;           // 64-col half within the B subtile
    const int quad = lane >> 4;
    const int cl   = lane & 15;

    // staging: per kb each wave copies 1 KB of each of A, B0, B1
    // (3 x 1-KB contiguous global_load_lds; pure linear copy, 8 waves tile 8 KB)
    const unsigned char* gA  = F + (size_t)f * FSZ + (size_t)bi  * OPB + wave * 1024 + lane * 16;
    const unsigned char* gB0 = F + (size_t)f * FSZ + (size_t)bj0 * OPB + wave * 1024 + lane * 16;
    const unsigned char* gB1 = F + (size_t)f * FSZ + (size_t)bj1 * OPB + wave * 1024 + lane * 16;
    unsigned char* lA  = As[0] + wave * 1024 + lane * 16;
    unsigned char* lB0 = Bs[0] + wave * 1024 + lane * 16;
    unsigned char* lB1 = Bs[0] + 8192 + wave * 1024 + lane * 16;

    floatx4 acc[4][4];
    const floatx4 z4 = {0.f, 0.f, 0.f, 0.f};
    #pragma unroll
    for (int mi = 0; mi < 4; ++mi)
        #pragma unroll
        for (int nj = 0; nj < 4; ++nj) acc[mi][nj] = z4;

    // frag read bases (linear, conflict-free: wave reads contiguous KBs)
    const unsigned char* aF = As[0] + (wm * 4) * 1024 + quad * 256 + cl * 16;
    const unsigned char* bF = Bs[0] + sb * 8192 + (hf * 4) * 1024 + quad * 256 + cl * 16;

    // ---- prologue: stage kb 0 (3 loads/wave in flight) ----
    async_ld16(gA, lA);
    async_ld16(gB0, lB0);
    async_ld16(gB1, lB1);
    gA += PAN; gB0 += PAN; gB1 += PAN;

    #pragma unroll
    for (int kb = 0; kb < 16; ++kb) {
        const int cur = kb & 1;
        const int nxt = cur ^ 1;
        if (kb < 15) {
            async_ld16(gA,  lA  + nxt * 8192);
            async_ld16(gB0, lB0 + nxt * 16384);
            async_ld16(gB1, lB1 + nxt * 16384);
            gA += PAN; gB0 += PAN; gB1 += PAN;
            asm volatile("s_waitcnt vmcnt(3)" ::: "memory");   // this wave's kb loads
        } else {
            asm volatile("s_waitcnt vmcnt(0)" ::: "memory");
        }
        __builtin_amdgcn_s_barrier();        // all waves' kb data in LDS
        __builtin_amdgcn_sched_barrier(0);   // keep ds_reads below the barrier

        const unsigned char* aB = aF + cur * 8192;
        const unsigned char* bB = bF + cur * 16384;

        longx2 bfr[4];
        #pragma unroll
        for (int nj = 0; nj < 4; ++nj)
            bfr[nj] = as_l2(*(const intx4*)(bB + nj * 1024));
        __builtin_amdgcn_s_setprio(1);
        #pragma unroll
        for (int mi = 0; mi < 4; ++mi) {
            longx2 afr = as_l2(*(const intx4*)(aB + mi * 1024));
            #pragma unroll
            for (int nj = 0; nj < 4; ++nj) {
                acc[mi][nj] = __builtin_amdgcn_mfma_f32_16x16x32_fp8_fp8(
                    afr[0], bfr[nj][0], acc[mi][nj], 0, 0, 0);
                acc[mi][nj] = __builtin_amdgcn_mfma_f32_16x16x32_fp8_fp8(
                    afr[1], bfr[nj][1], acc[mi][nj], 0, 0, 0);
            }
        }
        __builtin_amdgcn_s_setprio(0);
        __builtin_amdgcn_sched_barrier(0);   // keep reads/MFMA above the barrier
        __builtin_amdgcn_s_barrier();        // buf[cur] free for next prefetch
    }

    // ---- epilogue: e = exp(acc*EXPF), eye mask (diag, subtile 0 only),
    //      block-local LDS reduction, conflict-free partial stores ----
    __syncthreads();                      // all frag reads done; As reusable
    float* red = (float*)As;              // 8 KB needed, 16 KB available
    // layout (floats): [0..512)     rowR: wn*128 + rowLoc       (sum wn-pairs later)
    //                  [512..1024)  rowN
    //                  [1024..1536) colR: wm*256 + sb*128 + colInSub (sum wm later)
    //                  [1536..2048) colN
    // every entry written by exactly one lane -> plain ds_write, no init.

    const int colTileW = (sb ? bj1 : bj0) * 128;
    int   colgv[4];
    float wRcv[4];
    #pragma unroll
    for (int nj = 0; nj < 4; ++nj) {
        colgv[nj] = colTileW + hf * 64 + nj * 16 + cl;
        wRcv[nj]  = (label[colgv[nj]] != 0) ? 1.0f : 0.0f;
    }

    float colRa[4] = {0.f, 0.f, 0.f, 0.f};
    float colNa[4] = {0.f, 0.f, 0.f, 0.f};
    const bool eyeW = diag && (sb == 0);

    #pragma unroll
    for (int mi = 0; mi < 4; ++mi) {
        #pragma unroll
        for (int r = 0; r < 4; ++r) {
            const int rowLoc = wm * 64 + mi * 16 + quad * 4 + r;   // C/D: row=quad*4+reg
            const int rowg   = rowTile + rowLoc;
            const float wRr  = (label[rowg] != 0) ? 1.0f : 0.0f;
            float pR = 0.f, pN = 0.f;
            #pragma unroll
            for (int nj = 0; nj < 4; ++nj) {
                float c = acc[mi][nj][r];
                float e = __expf(c * EXPF);
                if (eyeW) e = (rowg == colgv[nj]) ? 0.0f : e;      // eye mask
                pR += wRcv[nj] * e;
                pN += (1.0f - wRcv[nj]) * e;
                colRa[nj] += wRr * e;
                colNa[nj] += (1.0f - wRr) * e;
            }
            #pragma unroll
            for (int m = 1; m < 16; m <<= 1) {        // reduce the 16 cl lanes
                pR += __shfl_xor(pR, m);
                pN += __shfl_xor(pN, m);
            }
            if (cl == 0) {
                red[wn * 128 + rowLoc]       = pR;
                red[512 + wn * 128 + rowLoc] = pN;
            }
        }
    }

    #pragma unroll
    for (int nj = 0; nj < 4; ++nj) {
        float cR = colRa[nj], cN = colNa[nj];
        cR += __shfl_xor(cR, 16); cN += __shfl_xor(cN, 16);       // reduce quads
        cR += __shfl_xor(cR, 32); cN += __shfl_xor(cN, 32);
        if (quad == 0) {
            const int ci = wm * 256 + sb * 128 + hf * 64 + nj * 16 + cl;
            red[1024 + ci] = cR;
            red[1536 + ci] = cN;
        }
    }

    __syncthreads();
    // P layout: [f][u(R=0,N=1)][slot 0..63][g 0..8191]
    float* Pr = P + ((size_t)f * 2 + 0) * (size_t)NTILE * BATCH;
    float* Pn = P + ((size_t)f * 2 + 1) * (size_t)NTILE * BATCH;
    if (tid < 128) {
        // row-parts: subtile 0 = wn 0+1, subtile 1 = wn 2+3
        Pr[(size_t)bj0 * BATCH + rowTile + tid] = red[tid]       + red[128 + tid];
        Pn[(size_t)bj0 * BATCH + rowTile + tid] = red[512 + tid] + red[640 + tid];
        if (has1) {
            Pr[(size_t)bj1 * BATCH + rowTile + tid] = red[256 + tid] + red[384 + tid];
            Pn[(size_t)bj1 * BATCH + rowTile + tid] = red[768 + tid] + red[896 + tid];
        }
        // col-parts: sum the two wm halves
        if (!diag) {
            Pr[(size_t)bi * BATCH + bj0 * 128 + tid] = red[1024 + tid] + red[1280 + tid];
            Pn[(size_t)bi * BATCH + bj0 * 128 + tid] = red[1536 + tid] + red[1792 + tid];
        }
        if (has1) {
            Pr[(size_t)bi * BATCH + bj1 * 128 + tid] = red[1152 + tid] + red[1408 + tid];
            Pn[(size_t)bi * BATCH + bj1 * 128 + tid] = red[1664 + tid] + red[1920 + tid];
        }
    }
}

// -------- final: 64-slot partial reduce + per-row loss + global reduce --------
__global__ __launch_bounds__(256) void loss_kernel(const float* __restrict__ P,
                                                   const int* __restrict__ label,
                                                   float* __restrict__ out) {
    const int idx = blockIdx.x * 256 + threadIdx.x;   // 0..16383 = (f, i)
    const int f = idx >> 13;
    const int i = idx & (BATCH - 1);
    const int lab = label[i];
    const float* Pr = P + ((size_t)f * 2 + 0) * (size_t)NTILE * BATCH;
    const float* Pn = Pr + (size_t)NTILE * BATCH;
    float sR = 0.f, sN = 0.f;
    #pragma unroll 8
    for (int s = 0; s < NTILE; ++s) {
        sR += Pr[(size_t)s * BATCH + i];
        sN += Pn[(size_t)s * BATCH + i];
    }
    const float own = lab ? sR : sN;
    const float oth = lab ? sN : sR;
    float t = -logf(own / (own + oth) + 1e-8f) * (1.0f / 4096.0f);
    #pragma unroll
    for (int m = 32; m >= 1; m >>= 1) t += __shfl_xor(t, m);
    __shared__ float red[4];
    if ((threadIdx.x & 63) == 0) red[threadIdx.x >> 6] = t;
    __syncthreads();
    if (threadIdx.x == 0) atomicAdd(out, red[0] + red[1] + red[2] + red[3]);
}

extern "C" void kernel_launch(void* const* d_in, const int* in_sizes, int n_in,
                              void* d_out, int out_size, void* d_ws, size_t ws_size,
                              hipStream_t stream) {
    const float* text  = (const float*)d_in[0];
    const float* image = (const float*)d_in[1];
    const int*   label = (const int*)d_in[2];
    float* out = (float*)d_out;

    // workspace: Fn[2][16][64rb][8KB] fp8 (16 MB), then P[2][2][64][8192] f32 (16 MB)
    unsigned char* Fn = (unsigned char*)d_ws;
    float* P = (float*)((char*)d_ws + (size_t)2 * BATCH * DIM);

    hipMemsetAsync(out, 0, sizeof(float), stream);

    dim3 ngrid(BATCH / 32, 2);
    norm_kernel<<<ngrid, 256, 0, stream>>>(text, image, Fn);

    dim3 grid(NPAIR, 1, 2);
    sim_kernel<<<grid, 512, 0, stream>>>(Fn, label, P);

    loss_kernel<<<(2 * BATCH) / 256, 256, 0, stream>>>(P, label, out);
}